// Round 5
// baseline (1022.991 us; speedup 1.0000x reference)
//
#include <hip/hip_runtime.h>
#include <hip/hip_bf16.h>
#include <stdint.h>

// MPO linear: out = x @ W^T + bias, W[m1*64+m2, n1*64+n2] = sum_r c1[m1,n1,r] c2[r,m2,n2]
// R8: faithful m201 8-phase schedule for the 256x256 GEMM (proven 62% MfmaUtil /
//     1563-1728 TF on identical geometry). Per phase: {asm ds_reads, stage,
//     [lgkm(8) if 12 reads], s_barrier, lgkm(0)+sched_barrier, setprio(1),
//     16 MFMA, setprio(0), sched_barrier, s_barrier}. One vmcnt(0) per K-tile
//     at P3, after all 8 next-tile loads were issued in P0/P1 (>=2 phases of
//     slack -> no stall). Lockstep barriers (8/K-tile) give pipe-level overlap:
//     MFMA pipe executes phase p's cluster while waves issue p+1's reads.
//     LDS: [2 buf][256 rows][64 shorts]; rows = 128 B = 8 x 16B chunks;
//     swizzle chunk ^= (row&7) -> af/bf ds_read_b128 conflict-free
//     (bank = chunk*4; (quad^ (r&7)) covers each 4-bank group 8x = minimum).
//     Stage: linear gl2lds dest, source chunk = (lane&7)^(lane>>3).

#define TOKENS 8192
#define DIN    4096
#define DOUT   4096
#define RANK   256
#define GEMM_K 4096

typedef __attribute__((ext_vector_type(8))) short   short8;
typedef __attribute__((ext_vector_type(4))) float   floatx4;

__device__ __forceinline__ unsigned short f2bf(float f) {
  union { float f; unsigned u; } v; v.f = f;
  unsigned r = v.u + 0x7FFFu + ((v.u >> 16) & 1u);  // round-to-nearest-even
  return (unsigned short)(r >> 16);
}

__device__ __forceinline__ void gl2lds16(const void* g, void* l) {
  __builtin_amdgcn_global_load_lds(
      (const __attribute__((address_space(1))) unsigned int*)g,
      (__attribute__((address_space(3))) unsigned int*)l,
      16, 0, 0);
}

// LDS byte offset of a generic pointer (AS3 pointers are 32-bit offsets).
__device__ __forceinline__ unsigned ldsaddr(const void* p) {
  return (unsigned)(size_t)(const __attribute__((address_space(3))) char*)p;
}

// ---- fp32 -> bf16 convert, n multiple of 2048 ----
__global__ __launch_bounds__(256) void k_f32_to_bf16(const float* __restrict__ src,
                                                     unsigned short* __restrict__ dst,
                                                     int n) {
  int i = (blockIdx.x * 256 + threadIdx.x) * 8;
  if (i >= n) return;
  float4 a = *(const float4*)(src + i);
  float4 b = *(const float4*)(src + i + 4);
  short8 o;
  o[0] = (short)f2bf(a.x); o[1] = (short)f2bf(a.y);
  o[2] = (short)f2bf(a.z); o[3] = (short)f2bf(a.w);
  o[4] = (short)f2bf(b.x); o[5] = (short)f2bf(b.y);
  o[6] = (short)f2bf(b.z); o[7] = (short)f2bf(b.w);
  *(short8*)(dst + i) = o;
}

// ---- core2 [256][4096] f32  ->  c2t [4096][256] bf16 (LDS tile transpose) ----
__global__ __launch_bounds__(256) void k_transpose_c2(const float* __restrict__ c2,
                                                      unsigned short* __restrict__ c2t) {
  __shared__ float tile[64][65];
  const int p0 = blockIdx.x * 64;
  const int r0 = blockIdx.y * 64;
  {
    const int px = threadIdx.x & 63;
    const int rb = threadIdx.x >> 6;           // 0..3
    for (int s = 0; s < 16; ++s) {
      int r = rb + s * 4;
      tile[r][px] = c2[(size_t)(r0 + r) * 4096 + p0 + px];
    }
  }
  __syncthreads();
  {
    const int rx = threadIdx.x & 63;
    const int pb = threadIdx.x >> 6;
    for (int s = 0; s < 16; ++s) {
      int p = pb + s * 4;
      c2t[(size_t)(p0 + p) * 256 + r0 + rx] = f2bf(tile[rx][p]);
    }
  }
}

// ---- R1-proven 128x128 BK=32 GEMM (kept for the small W-GEMM, K=256) ----
template <int K, int BK, bool PERM>
__global__ __launch_bounds__(256) void k_gemm_bt(const unsigned short* __restrict__ A,
                                                 const unsigned short* __restrict__ B,
                                                 float* __restrict__ outF,
                                                 unsigned short* __restrict__ outW,
                                                 const float* __restrict__ bias) {
  constexpr int ROWB   = BK * 2;
  constexpr int CM     = BK / 8 - 1;
  constexpr int ROUNDS = BK / 16;
  constexpr int KK     = BK / 32;

  __shared__ __align__(16) unsigned short As[128 * BK];
  __shared__ __align__(16) unsigned short Bs[128 * BK];

  const int tid  = threadIdx.x;
  const int lane = tid & 63;
  const int wave = tid >> 6;
  const int m0 = blockIdx.y * 128;
  const int n0 = blockIdx.x * 128;

  const int waveM = (wave & 1) * 64;
  const int waveN = (wave >> 1) * 64;
  const int l15  = lane & 15;
  const int quad = lane >> 4;

  floatx4 acc[4][4];
#pragma unroll
  for (int i = 0; i < 4; ++i)
#pragma unroll
    for (int j = 0; j < 4; ++j) acc[i][j] = (floatx4)0.0f;

  const size_t rowBytes = (size_t)K * 2;

  for (int kt = 0; kt < K; kt += BK) {
    __syncthreads();
#pragma unroll
    for (int j = 0; j < ROUNDS; ++j) {
      const int flat = (j * 4 + wave) * 1024 + lane * 16;
      const int row  = flat / ROWB;
      const int c    = (flat >> 4) & CM;
      const int cs   = c ^ (row & CM);
      const int ldsb = (j * 4 + wave) * 1024;
      gl2lds16((const char*)A + (size_t)(m0 + row) * rowBytes + (size_t)kt * 2 + cs * 16,
               (char*)As + ldsb);
      gl2lds16((const char*)B + (size_t)(n0 + row) * rowBytes + (size_t)kt * 2 + cs * 16,
               (char*)Bs + ldsb);
    }
    __syncthreads();

#pragma unroll
    for (int kk = 0; kk < KK; ++kk) {
      short8 af[4], bfr[4];
#pragma unroll
      for (int mi = 0; mi < 4; ++mi) {
        const int row = waveM + mi * 16 + l15;
        const int cs  = (kk * 4 + quad) ^ (row & CM);
        af[mi] = *(const short8*)(As + row * BK + cs * 8);
      }
#pragma unroll
      for (int ni = 0; ni < 4; ++ni) {
        const int row = waveN + ni * 16 + l15;
        const int cs  = (kk * 4 + quad) ^ (row & CM);
        bfr[ni] = *(const short8*)(Bs + row * BK + cs * 8);
      }
#pragma unroll
      for (int mi = 0; mi < 4; ++mi)
#pragma unroll
        for (int ni = 0; ni < 4; ++ni)
          acc[mi][ni] = __builtin_amdgcn_mfma_f32_16x16x32_bf16(af[mi], bfr[ni], acc[mi][ni], 0, 0, 0);
    }
  }

  if (!PERM) {
#pragma unroll
    for (int ni = 0; ni < 4; ++ni) {
      const int col = n0 + waveN + ni * 16 + l15;
      const float bv = bias[col];
#pragma unroll
      for (int mi = 0; mi < 4; ++mi) {
        const int rowb = m0 + waveM + mi * 16 + quad * 4;
#pragma unroll
        for (int r = 0; r < 4; ++r)
          outF[(size_t)(rowb + r) * DOUT + col] = acc[mi][ni][r] + bv;
      }
    }
  } else {
#pragma unroll
    for (int ni = 0; ni < 4; ++ni) {
      const int bcol = n0 + waveN + ni * 16 + l15;
      const int m2 = bcol >> 6, n2 = bcol & 63;
#pragma unroll
      for (int mi = 0; mi < 4; ++mi) {
        const int arow0 = m0 + waveM + mi * 16 + quad * 4;
#pragma unroll
        for (int r = 0; r < 4; ++r) {
          const int arow = arow0 + r;
          const int m1 = arow >> 6, n1 = arow & 63;
          outW[(size_t)(m1 * 64 + m2) * 4096 + (n1 * 64 + n2)] = f2bf(acc[mi][ni][r]);
        }
      }
    }
  }
}

// ---- R8: 256x256 8-phase (m201 template) bf16 GEMM, C = A @ B^T + bias ----
// 512 thr = 8 waves (2M x 4N), wave tile 128x64, BK=64, double-buffered.
__global__ __launch_bounds__(512, 2) void k_gemm256(const unsigned short* __restrict__ A,
                                                    const unsigned short* __restrict__ B,
                                                    float* __restrict__ out,
                                                    const float* __restrict__ bias) {
  __shared__ __align__(1024) unsigned short As[2][16384];  // [buf][256 rows * 64]
  __shared__ __align__(1024) unsigned short Bs[2][16384];

  const int tid  = threadIdx.x;
  const int lane = tid & 63;
  const int wave = tid >> 6;

  // XCD-bijective swizzle: 512 blocks, 8 XCDs, 64-block chunks.
  const int id  = blockIdx.y * gridDim.x + blockIdx.x;
  const int nid = (id & 7) * 64 + (id >> 3);
  const int bx  = nid & 15;
  const int by  = nid >> 4;
  const int m0  = by * 256;
  const int n0  = bx * 256;

  const int waveM = (wave >> 2) << 7;   // 0 or 128
  const int waveN = (wave & 3) << 6;    // 0,64,128,192
  const int l15   = lane & 15;
  const int quad  = lane >> 4;

  // read-side byte xor-part for kk=0 (kk=1 = ^64); chunk ^= row&7, row&7 = l15&7
  const unsigned x0 = (unsigned)((quad ^ (l15 & 7)) * 16);
  // stage-side: lane l writes LDS chunk l&7 of row (+l>>3); source chunk pre-swizzled
  const int srow    = lane >> 3;                        // 0..7
  const int schunk16 = ((lane & 7) ^ (lane >> 3)) * 16; // source chunk byte offset

  floatx4 acc[8][4];
#pragma unroll
  for (int i = 0; i < 8; ++i)
#pragma unroll
    for (int j = 0; j < 4; ++j) acc[i][j] = (floatx4)0.0f;

  // fragment registers: afA = rows mh0, afB = rows mh1; bf0 = cols nh0, bf1 = nh1
  short8 afA[4][2], afB[4][2], bf0[2][2], bf1[2][2];

#define BARRIER() asm volatile("s_barrier" ::: "memory")
#define SCHED0()  __builtin_amdgcn_sched_barrier(0)

// stage half H (128 rows x 64 cols) of A-tile at k-offset KTN into buf BUF
#define SA(BUF, KTN, H)                                                           \
  {                                                                               \
    _Pragma("unroll")                                                             \
    for (int j_ = 0; j_ < 2; ++j_) {                                              \
      const char* src_ = (const char*)A +                                         \
          (size_t)(m0 + (H) * 128 + wave * 16 + j_ * 8 + srow) * 8192 +           \
          (size_t)(KTN) * 2 + schunk16;                                           \
      gl2lds16(src_, (char*)&As[BUF][0] + (H) * 16384 + wave * 2048 + j_ * 1024); \
    }                                                                             \
  }

#define SB(BUF, KTN, H)                                                           \
  {                                                                               \
    _Pragma("unroll")                                                             \
    for (int j_ = 0; j_ < 2; ++j_) {                                              \
      const char* src_ = (const char*)B +                                         \
          (size_t)(n0 + (H) * 128 + wave * 16 + j_ * 8 + srow) * 8192 +           \
          (size_t)(KTN) * 2 + schunk16;                                           \
      gl2lds16(src_, (char*)&Bs[BUF][0] + (H) * 16384 + wave * 2048 + j_ * 1024); \
    }                                                                             \
  }

// asm ds_read_b128: we own the lgkm counter (compiler emits no waits for these)
#define R_AF(DST, BUF, MH)                                                        \
  _Pragma("unroll")                                                               \
  for (int mi_ = 0; mi_ < 4; ++mi_)                                               \
    _Pragma("unroll")                                                             \
    for (int kk_ = 0; kk_ < 2; ++kk_)                                             \
      asm volatile("ds_read_b128 %0, %1" : "=v"(DST[mi_][kk_])                    \
          : "v"(ldsaddr(&As[BUF][0]) +                                            \
                (unsigned)((waveM + (MH) * 64 + mi_ * 16 + l15) * 128) +          \
                (x0 ^ (unsigned)(kk_ * 64))));

#define R_BF(DST, BUF, NH)                                                        \
  _Pragma("unroll")                                                               \
  for (int ni_ = 0; ni_ < 2; ++ni_)                                               \
    _Pragma("unroll")                                                             \
    for (int kk_ = 0; kk_ < 2; ++kk_)                                             \
      asm volatile("ds_read_b128 %0, %1" : "=v"(DST[ni_][kk_])                    \
          : "v"(ldsaddr(&Bs[BUF][0]) +                                            \
                (unsigned)((waveN + (NH) * 32 + ni_ * 16 + l15) * 128) +          \
                (x0 ^ (unsigned)(kk_ * 64))));

#define LGKM0() { asm volatile("s_waitcnt lgkmcnt(0)"); SCHED0(); }
#define LGKM8() { asm volatile("s_waitcnt lgkmcnt(8)"); }

// 16 MFMA: quadrant (MH, NH) x K=64. kk outer -> 8 independent chains of 2.
#define MM(MH, NH, AF, BF)                                                        \
  __builtin_amdgcn_s_setprio(1);                                                  \
  _Pragma("unroll")                                                               \
  for (int kk_ = 0; kk_ < 2; ++kk_)                                               \
    _Pragma("unroll")                                                             \
    for (int mi_ = 0; mi_ < 4; ++mi_)                                             \
      _Pragma("unroll")                                                           \
      for (int ni_ = 0; ni_ < 2; ++ni_)                                           \
        acc[(MH) * 4 + mi_][(NH) * 2 + ni_] =                                     \
            __builtin_amdgcn_mfma_f32_16x16x32_bf16(                              \
                AF[mi_][kk_], BF[ni_][kk_], acc[(MH) * 4 + mi_][(NH) * 2 + ni_],  \
                0, 0, 0);                                                         \
  __builtin_amdgcn_s_setprio(0);                                                  \
  SCHED0();

  // ITER: compute K-tile in buf C; stage K-tile at k-offset KTN into buf 1-C.
#define ITER(C, KTN)                                                              \
  { /* P0 */                                                                      \
    R_AF(afA, C, 0)                                                               \
    R_BF(bf0, C, 0)                                                               \
    SA(1 - (C), KTN, 0)                                                           \
    SA(1 - (C), KTN, 1)                                                           \
    LGKM8()                                                                       \
    BARRIER();                                                                    \
    LGKM0()                                                                       \
    MM(0, 0, afA, bf0)                                                            \
    BARRIER();                                                                    \
    /* P1 */                                                                      \
    R_AF(afB, C, 1)                                                               \
    SB(1 - (C), KTN, 0)                                                           \
    SB(1 - (C), KTN, 1)                                                           \
    BARRIER();                                                                    \
    LGKM0()                                                                       \
    MM(1, 0, afB, bf0)                                                            \
    BARRIER();                                                                    \
    /* P2 */                                                                      \
    R_BF(bf1, C, 1)                                                               \
    BARRIER();                                                                    \
    LGKM0()                                                                       \
    MM(0, 1, afA, bf1)                                                            \
    BARRIER();                                                                    \
    /* P3 */                                                                      \
    asm volatile("s_waitcnt vmcnt(0)" ::: "memory");                              \
    BARRIER();                                                                    \
    MM(1, 1, afB, bf1)                                                            \
    BARRIER();                                                                    \
  }

  // prologue: stage tile0 into buf0, drain, barrier.
  SA(0, 0, 0) SA(0, 0, 1) SB(0, 0, 0) SB(0, 0, 1)
  asm volatile("s_waitcnt vmcnt(0)" ::: "memory");
  BARRIER();

  for (int kt = 0; kt < GEMM_K; kt += 128) {
    ITER(0, kt + 64)
    ITER(1, (kt + 128) & (GEMM_K - 1))   // wrap: harmless restage of tile 0
  }

#undef ITER
#undef MM
#undef LGKM8
#undef LGKM0
#undef R_BF
#undef R_AF
#undef SB
#undef SA
#undef SCHED0
#undef BARRIER

  // epilogue: C/D layout col = lane&15, row = quad*4 + reg (proven m89/m91).
  // acc[a][b]: row = waveM + (a>>2)*64 + (a&3)*16; col = waveN + (b>>1)*32 + (b&1)*16.
#pragma unroll
  for (int b = 0; b < 4; ++b) {
    const int col = n0 + waveN + (b >> 1) * 32 + (b & 1) * 16 + l15;
    const float bv = bias[col];
#pragma unroll
    for (int a = 0; a < 8; ++a) {
      const int row0 = m0 + waveM + (a >> 2) * 64 + (a & 3) * 16 + quad * 4;
#pragma unroll
      for (int r = 0; r < 4; ++r)
        out[(size_t)(row0 + r) * DOUT + col] = acc[a][b][r] + bv;
    }
  }
}

extern "C" void kernel_launch(void* const* d_in, const int* in_sizes, int n_in,
                              void* d_out, int out_size, void* d_ws, size_t ws_size,
                              hipStream_t stream) {
  const float* x    = (const float*)d_in[0];
  const float* c1   = (const float*)d_in[1];
  const float* c2   = (const float*)d_in[2];
  const float* bias = (const float*)d_in[3];
  float* out = (float*)d_out;

  // workspace layout (100 MB total)
  char* ws = (char*)d_ws;
  unsigned short* xb  = (unsigned short*)ws;                               // 67108864 B
  unsigned short* Wb  = (unsigned short*)(ws + 67108864);                  // 33554432 B
  unsigned short* c1b = (unsigned short*)(ws + 67108864 + 33554432);       //  2097152 B
  unsigned short* c2t = (unsigned short*)(ws + 67108864 + 33554432 + 2097152);  // 2097152 B

  k_f32_to_bf16<<<(TOKENS * DIN) / 2048, 256, 0, stream>>>(x, xb, TOKENS * DIN);
  k_f32_to_bf16<<<(64 * 64 * RANK) / 2048, 256, 0, stream>>>(c1, c1b, 64 * 64 * RANK);
  k_transpose_c2<<<dim3(64, 4), 256, 0, stream>>>(c2, c2t);

  // t-GEMM: [4096 x 256] @ [4096 x 256]^T -> W bf16 (permuted store), BK=32 (R1-proven)
  k_gemm_bt<RANK, 32, true><<<dim3(32, 32), 256, 0, stream>>>(c1b, c2t, nullptr, Wb, nullptr);
  // main GEMM: 256^2 8-phase (m201 template)
  k_gemm256<<<dim3(16, 32), 512, 0, stream>>>(xb, Wb, out, bias);
}

// Round 6
// 484.237 us; speedup vs baseline: 2.1126x; 2.1126x over previous
//
#include <hip/hip_runtime.h>
#include <hip/hip_bf16.h>
#include <stdint.h>

// MPO linear: out = x @ W^T + bias, W[m1*64+m2, n1*64+n2] = sum_r c1[m1,n1,r] c2[r,m2,n2]
// R9: REVERT to R7's verified GEMM (488us total / 250us GEMM; R8's 8-phase
//     lockstep port regressed 3.2x — vmcnt(0) with ~2-phase slack exposed
//     loaded-HBM latency every iter and thrashed L2, FETCH 300->714MB).
//     Changes vs R7 (both bounded, outside the verified sync structure):
//     (1) k_prep: x-convert + c1-convert + c2-transpose fused into ONE kernel
//         via disjoint block ranges (branch bodies = the verified kernels,
//         untouched). Launch chain 6 -> 4 kernels. Diagnostic for the ~238us
//         of non-GEMM time (launch gaps vs kernel time).
//     (2) in each GEMM window, STAGE is issued before the ds_reads (identical
//         lgkm/vmcnt ledgers — lgkm counts only ds_reads, vmcnt order
//         unchanged; strictly earlier HBM issue -> slightly more slack).

#define TOKENS 8192
#define DIN    4096
#define DOUT   4096
#define RANK   256
#define GEMM_K 4096

typedef __attribute__((ext_vector_type(8))) short   short8;
typedef __attribute__((ext_vector_type(4))) float   floatx4;

__device__ __forceinline__ unsigned short f2bf(float f) {
  union { float f; unsigned u; } v; v.f = f;
  unsigned r = v.u + 0x7FFFu + ((v.u >> 16) & 1u);  // round-to-nearest-even
  return (unsigned short)(r >> 16);
}

__device__ __forceinline__ void gl2lds16(const void* g, void* l) {
  __builtin_amdgcn_global_load_lds(
      (const __attribute__((address_space(1))) unsigned int*)g,
      (__attribute__((address_space(3))) unsigned int*)l,
      16, 0, 0);
}

// LDS byte offset of a generic pointer (AS3 pointers are 32-bit offsets).
__device__ __forceinline__ unsigned ldsaddr(const void* p) {
  return (unsigned)(size_t)(const __attribute__((address_space(3))) char*)p;
}

// ---- R9 prep kernel: three disjoint block ranges, one launch ----
// blocks [0, NBX)            : x  f32->bf16, 2048 elems/block
// blocks [NBX, NBX+NBC1)     : c1 f32->bf16, 2048 elems/block
// blocks [NBX+NBC1, +256)    : c2 [256][4096] -> c2t [4096][256] bf16 transpose
#define NBX  16384
#define NBC1 512

__global__ __launch_bounds__(256) void k_prep(const float* __restrict__ x,
                                              const float* __restrict__ c1,
                                              const float* __restrict__ c2,
                                              unsigned short* __restrict__ xb,
                                              unsigned short* __restrict__ c1b,
                                              unsigned short* __restrict__ c2t) {
  __shared__ float tile[64][65];
  const int b = blockIdx.x;
  if (b < NBX + NBC1) {
    const float* src = (b < NBX) ? x : c1;
    unsigned short* dst = (b < NBX) ? xb : c1b;
    const int lb = (b < NBX) ? b : (b - NBX);
    int i = (lb * 256 + (int)threadIdx.x) * 8;
    float4 a = *(const float4*)(src + i);
    float4 c = *(const float4*)(src + i + 4);
    short8 o;
    o[0] = (short)f2bf(a.x); o[1] = (short)f2bf(a.y);
    o[2] = (short)f2bf(a.z); o[3] = (short)f2bf(a.w);
    o[4] = (short)f2bf(c.x); o[5] = (short)f2bf(c.y);
    o[6] = (short)f2bf(c.z); o[7] = (short)f2bf(c.w);
    *(short8*)(dst + i) = o;
    return;
  }
  // transpose branch (verified k_transpose_c2 body)
  const int b2 = b - (NBX + NBC1);
  const int p0 = (b2 & 63) * 64;
  const int r0 = (b2 >> 6) * 64;
  {
    const int px = threadIdx.x & 63;
    const int rb = threadIdx.x >> 6;           // 0..3
    for (int s = 0; s < 16; ++s) {
      int r = rb + s * 4;
      tile[r][px] = c2[(size_t)(r0 + r) * 4096 + p0 + px];
    }
  }
  __syncthreads();
  {
    const int rx = threadIdx.x & 63;
    const int pb = threadIdx.x >> 6;
    for (int s = 0; s < 16; ++s) {
      int p = pb + s * 4;
      c2t[(size_t)(p0 + p) * 256 + r0 + rx] = f2bf(tile[rx][p]);
    }
  }
}

// ---- R1-proven 128x128 BK=32 GEMM (kept for the small W-GEMM, K=256) ----
template <int K, int BK, bool PERM>
__global__ __launch_bounds__(256) void k_gemm_bt(const unsigned short* __restrict__ A,
                                                 const unsigned short* __restrict__ B,
                                                 float* __restrict__ outF,
                                                 unsigned short* __restrict__ outW,
                                                 const float* __restrict__ bias) {
  constexpr int ROWB   = BK * 2;
  constexpr int CM     = BK / 8 - 1;
  constexpr int ROUNDS = BK / 16;
  constexpr int KK     = BK / 32;

  __shared__ __align__(16) unsigned short As[128 * BK];
  __shared__ __align__(16) unsigned short Bs[128 * BK];

  const int tid  = threadIdx.x;
  const int lane = tid & 63;
  const int wave = tid >> 6;
  const int m0 = blockIdx.y * 128;
  const int n0 = blockIdx.x * 128;

  const int waveM = (wave & 1) * 64;
  const int waveN = (wave >> 1) * 64;
  const int l15  = lane & 15;
  const int quad = lane >> 4;

  floatx4 acc[4][4];
#pragma unroll
  for (int i = 0; i < 4; ++i)
#pragma unroll
    for (int j = 0; j < 4; ++j) acc[i][j] = (floatx4)0.0f;

  const size_t rowBytes = (size_t)K * 2;

  for (int kt = 0; kt < K; kt += BK) {
    __syncthreads();
#pragma unroll
    for (int j = 0; j < ROUNDS; ++j) {
      const int flat = (j * 4 + wave) * 1024 + lane * 16;
      const int row  = flat / ROWB;
      const int c    = (flat >> 4) & CM;
      const int cs   = c ^ (row & CM);
      const int ldsb = (j * 4 + wave) * 1024;
      gl2lds16((const char*)A + (size_t)(m0 + row) * rowBytes + (size_t)kt * 2 + cs * 16,
               (char*)As + ldsb);
      gl2lds16((const char*)B + (size_t)(n0 + row) * rowBytes + (size_t)kt * 2 + cs * 16,
               (char*)Bs + ldsb);
    }
    __syncthreads();

#pragma unroll
    for (int kk = 0; kk < KK; ++kk) {
      short8 af[4], bfr[4];
#pragma unroll
      for (int mi = 0; mi < 4; ++mi) {
        const int row = waveM + mi * 16 + l15;
        const int cs  = (kk * 4 + quad) ^ (row & CM);
        af[mi] = *(const short8*)(As + row * BK + cs * 8);
      }
#pragma unroll
      for (int ni = 0; ni < 4; ++ni) {
        const int row = waveN + ni * 16 + l15;
        const int cs  = (kk * 4 + quad) ^ (row & CM);
        bfr[ni] = *(const short8*)(Bs + row * BK + cs * 8);
      }
#pragma unroll
      for (int mi = 0; mi < 4; ++mi)
#pragma unroll
        for (int ni = 0; ni < 4; ++ni)
          acc[mi][ni] = __builtin_amdgcn_mfma_f32_16x16x32_bf16(af[mi], bfr[ni], acc[mi][ni], 0, 0, 0);
    }
  }

  if (!PERM) {
#pragma unroll
    for (int ni = 0; ni < 4; ++ni) {
      const int col = n0 + waveN + ni * 16 + l15;
      const float bv = bias[col];
#pragma unroll
      for (int mi = 0; mi < 4; ++mi) {
        const int rowb = m0 + waveM + mi * 16 + quad * 4;
#pragma unroll
        for (int r = 0; r < 4; ++r)
          outF[(size_t)(rowb + r) * DOUT + col] = acc[mi][ni][r] + bv;
      }
    }
  } else {
#pragma unroll
    for (int ni = 0; ni < 4; ++ni) {
      const int bcol = n0 + waveN + ni * 16 + l15;
      const int m2 = bcol >> 6, n2 = bcol & 63;
#pragma unroll
      for (int mi = 0; mi < 4; ++mi) {
        const int arow0 = m0 + waveM + mi * 16 + quad * 4;
#pragma unroll
        for (int r = 0; r < 4; ++r) {
          const int arow = arow0 + r;
          const int m1 = arow >> 6, n1 = arow & 63;
          outW[(size_t)(m1 * 64 + m2) * 4096 + (n1 * 64 + n2)] = f2bf(acc[mi][ni][r]);
        }
      }
    }
  }
}

// ---- R7-verified: 256x256 pipelined bf16 GEMM, C = A @ B^T + bias ----
// 512 thr = 8 waves (2M x 4N), wave tile 128x64.
// LDS: As/Bs [2 buf][2 kh][256 rows][32 shorts] = 128 KiB.
// st_16x32 swizzle (proven conflict-free R5): chunk ^= (row>>2)&2.
// Wait ledger (per-wave ds_reads, issue order ...W3prev(8),W0(4),W1(8),...):
//   W0 LGKM(4) drains W3prev's 8 (af0,bfvA); W1 LGKM(8) drains W0's 4 (af1);
//   W2 LGKM(4) drains W1's 8; W3 LGKM(8) drains W2's 4.
// vmcnt(2) at W1/W3 drains staged sub-buffers 2 windows before first read.
__global__ __launch_bounds__(512, 2) void k_gemm256(const unsigned short* __restrict__ A,
                                                    const unsigned short* __restrict__ B,
                                                    float* __restrict__ out,
                                                    const float* __restrict__ bias) {
  __shared__ __align__(16) unsigned short As[2][2][8192];  // [buf][kh][256*32]
  __shared__ __align__(16) unsigned short Bs[2][2][8192];

  const int tid  = threadIdx.x;
  const int lane = tid & 63;
  const int wave = tid >> 6;

  // XCD-bijective swizzle: 512 blocks, 8 XCDs, 64-block chunks.
  const int id  = blockIdx.y * gridDim.x + blockIdx.x;
  const int nid = (id & 7) * 64 + (id >> 3);
  const int bx  = nid & 15;
  const int by  = nid >> 4;
  const int m0  = by * 256;
  const int n0  = bx * 256;

  const int waveM = (wave >> 2) << 7;   // 0 or 128
  const int waveN = (wave & 3) << 6;    // 0,64,128,192
  const int l15   = lane & 15;
  const int quad  = lane >> 4;

  const int rsw = (quad ^ ((l15 >> 2) & 2)) * 8;          // read-side swizzled chunk
  const int srow   = wave * 16 + (lane >> 2);             // stage row
  const int schunk = (lane & 3) ^ ((lane >> 4) & 2);      // stage source chunk

  floatx4 acc[8][4];
#pragma unroll
  for (int i = 0; i < 8; ++i)
#pragma unroll
    for (int j = 0; j < 4; ++j) acc[i][j] = (floatx4)0.0f;

  // double-buffered fragment registers (static names, rule #20)
  short8 af0[4], af1[4], bfvA[4], bfvB[4];

#define STAGE(LDSHALF, GBASE, R0, KBYTE)                                          \
  {                                                                               \
    _Pragma("unroll")                                                             \
    for (int j_ = 0; j_ < 2; ++j_) {                                              \
      const char* src_ = (const char*)(GBASE) +                                   \
          (size_t)((R0) + j_ * 128 + srow) * (size_t)(GEMM_K * 2) +               \
          (size_t)(KBYTE) + schunk * 16;                                          \
      gl2lds16(src_, (char*)(LDSHALF) + j_ * 8192 + wave * 1024);                 \
    }                                                                             \
  }

// asm ds_read_b128: compiler emits NO waitcnt for these outputs — we own it.
#define READ_AF(DST, BUF, KH, MH)                                                 \
  _Pragma("unroll")                                                               \
  for (int i_ = 0; i_ < 4; ++i_)                                                  \
    asm volatile("ds_read_b128 %0, %1" : "=v"(DST[i_])                            \
        : "v"(ldsaddr(&As[BUF][KH][0] +                                           \
                      (waveM + ((MH) * 4 + i_) * 16 + l15) * 32 + rsw)));

#define READ_BF(DST, BUF, KH)                                                     \
  _Pragma("unroll")                                                               \
  for (int n_ = 0; n_ < 4; ++n_)                                                  \
    asm volatile("ds_read_b128 %0, %1" : "=v"(DST[n_])                            \
        : "v"(ldsaddr(&Bs[BUF][KH][0] + (waveN + n_ * 16 + l15) * 32 + rsw)));

// counted lgkm wait + full sched fence (rule #18)
#define LGKM4() { asm volatile("s_waitcnt lgkmcnt(4)"); __builtin_amdgcn_sched_barrier(0); }
#define LGKM8() { asm volatile("s_waitcnt lgkmcnt(8)"); __builtin_amdgcn_sched_barrier(0); }

#define MFMA16(AF, BF, MH)                                                        \
  __builtin_amdgcn_s_setprio(1);                                                  \
  _Pragma("unroll")                                                               \
  for (int i_ = 0; i_ < 4; ++i_)                                                  \
    _Pragma("unroll")                                                             \
    for (int n_ = 0; n_ < 4; ++n_)                                                \
      acc[(MH) * 4 + i_][n_] = __builtin_amdgcn_mfma_f32_16x16x32_bf16(           \
          AF[i_], BF[n_], acc[(MH) * 4 + i_][n_], 0, 0, 0);                       \
  __builtin_amdgcn_s_setprio(0);

#define SYNC2()                                                                   \
  asm volatile("s_waitcnt vmcnt(2)" ::: "memory");                                \
  asm volatile("s_barrier" ::: "memory");

  // KTILE(C, KTN): compute K-range held in buf C; stage k-offset KTN into buf 1-C.
  // R9: STAGE issued before the window's ds_reads (ledger-identical, earlier HBM issue).
#define KTILE(C, KTN)                                                             \
  { /* W0: stage A0'; read af1(C,kh0,mh1); wait W3prev reads; MFMA mh0 */         \
    STAGE(&As[1 - (C)][0][0], A, m0, (KTN) * 2)                                   \
    READ_AF(af1, C, 0, 1)                                                         \
    LGKM4()                                                                       \
    MFMA16(af0, bfvA, 0)                                                          \
    /* W1: sync; stage B0'; read af0(C,kh1,mh0)+bfvB(C,kh1); MFMA mh1 */          \
    SYNC2()                                                                       \
    STAGE(&Bs[1 - (C)][0][0], B, n0, (KTN) * 2)                                   \
    READ_AF(af0, C, 1, 0)                                                         \
    READ_BF(bfvB, C, 1)                                                           \
    LGKM8()                                                                       \
    MFMA16(af1, bfvA, 1)                                                          \
    /* W2: stage A1'; read af1(C,kh1,mh1); MFMA mh0 */                            \
    STAGE(&As[1 - (C)][1][0], A, m0, (KTN) * 2 + 64)                              \
    READ_AF(af1, C, 1, 1)                                                         \
    LGKM4()                                                                       \
    MFMA16(af0, bfvB, 0)                                                          \
    /* W3: sync; stage B1'; read next-tile af0+bfvA(1-C,kh0); MFMA mh1 */         \
    SYNC2()                                                                       \
    STAGE(&Bs[1 - (C)][1][0], B, n0, (KTN) * 2 + 64)                              \
    READ_AF(af0, 1 - (C), 0, 0)                                                   \
    READ_BF(bfvA, 1 - (C), 0)                                                     \
    LGKM8()                                                                       \
    MFMA16(af1, bfvB, 1)                                                          \
  }

  // prologue: stage tile0 into buf0, drain fully once, prime W0's operands.
  STAGE(&As[0][0][0], A, m0, 0);
  STAGE(&Bs[0][0][0], B, n0, 0);
  STAGE(&As[0][1][0], A, m0, 64);
  STAGE(&Bs[0][1][0], B, n0, 64);
  asm volatile("s_waitcnt vmcnt(0)" ::: "memory");
  asm volatile("s_barrier" ::: "memory");
  READ_AF(af0, 0, 0, 0)   // drained by first W0's LGKM4
  READ_BF(bfvA, 0, 0)

  for (int kt = 0; kt < GEMM_K; kt += 128) {
    KTILE(0, kt + 64)
    const int ktn1 = (kt + 128 < GEMM_K) ? (kt + 128) : 0;   // wrap: harmless restage
    KTILE(1, ktn1)
  }

#undef KTILE
#undef SYNC2
#undef MFMA16
#undef LGKM8
#undef LGKM4
#undef READ_BF
#undef READ_AF
#undef STAGE

  // epilogue: C/D layout col = lane&15, row = quad*4 + reg (proven m89/m91).
#pragma unroll
  for (int ni = 0; ni < 4; ++ni) {
    const int col = n0 + waveN + ni * 16 + l15;
    const float bv = bias[col];
#pragma unroll
    for (int mi = 0; mi < 8; ++mi) {
      const int row0 = m0 + waveM + mi * 16 + quad * 4;
#pragma unroll
      for (int r = 0; r < 4; ++r)
        out[(size_t)(row0 + r) * DOUT + col] = acc[mi][ni][r] + bv;
    }
  }
}

extern "C" void kernel_launch(void* const* d_in, const int* in_sizes, int n_in,
                              void* d_out, int out_size, void* d_ws, size_t ws_size,
                              hipStream_t stream) {
  const float* x    = (const float*)d_in[0];
  const float* c1   = (const float*)d_in[1];
  const float* c2   = (const float*)d_in[2];
  const float* bias = (const float*)d_in[3];
  float* out = (float*)d_out;

  // workspace layout (100 MB total)
  char* ws = (char*)d_ws;
  unsigned short* xb  = (unsigned short*)ws;                               // 67108864 B
  unsigned short* Wb  = (unsigned short*)(ws + 67108864);                  // 33554432 B
  unsigned short* c1b = (unsigned short*)(ws + 67108864 + 33554432);       //  2097152 B
  unsigned short* c2t = (unsigned short*)(ws + 67108864 + 33554432 + 2097152);  // 2097152 B

  // prep: x-convert + c1-convert + c2-transpose in ONE launch (disjoint block ranges)
  k_prep<<<NBX + NBC1 + 256, 256, 0, stream>>>(x, c1, c2, xb, c1b, c2t);

  // t-GEMM: [4096 x 256] @ [4096 x 256]^T -> W bf16 (permuted store), BK=32 (R1-proven)
  k_gemm_bt<RANK, 32, true><<<dim3(32, 32), 256, 0, stream>>>(c1b, c2t, nullptr, Wb, nullptr);
  // main GEMM: R7-verified 256^2 pipeline with asm ds_read + counted lgkm
  k_gemm256<<<dim3(16, 32), 512, 0, stream>>>(xb, Wb, out, bias);
}